// Round 4
// baseline (30.581 us; speedup 1.0000x reference)
//
#include <hip/hip_runtime.h>
#include <hip/hip_bf16.h>
#include <math.h>

typedef __bf16 bf16;
typedef __bf16 bf16x8 __attribute__((ext_vector_type(8)));
typedef float  f32x4  __attribute__((ext_vector_type(4)));

static constexpr int kTokens = 32768;   // B*S = 8*4096
static constexpr int kH   = 768;
static constexpr int kC   = 64;
static constexpr int kNWr = 65;         // rows actually staged: 64 e1 cols + 1 sc col
static constexpr int kLDW = kH + 8;     // +8 bf16 pad: row stride 1552 B -> 2-way banks (free)

// ---------- prep: Wt[n][k] = W_e1^T (rows 0..63), row 64 = w_sc; b_sc scalar ----------
// Coalesced: consecutive lanes read consecutive W_e1 elements (one 256B row per wave).
__global__ void prep_kernel(const float* __restrict__ W_ct,
                            const float* __restrict__ b_ct,
                            const float* __restrict__ W_cd,
                            const float* __restrict__ b_cd,
                            const float* __restrict__ W_e1,
                            bf16* __restrict__ Wt,
                            float* __restrict__ bsc) {
    int gidx = blockIdx.x * blockDim.x + threadIdx.x;
    if (gidx < kH * kC) {                       // 49152: transpose-copy, coalesced reads
        int k = gidx >> 6;
        int n = gidx & 63;
        Wt[(size_t)n * kH + k] = (bf16)W_e1[gidx];
    } else if (gidx < kH * kC + kH) {           // 768 threads: w_sc = W_ct @ W_cd
        int k = gidx - kH * kC;
        float s = 0.f;
        #pragma unroll 8
        for (int c = 0; c < kC; ++c) s += W_ct[k * kC + c] * W_cd[c];
        Wt[(size_t)kC * kH + k] = (bf16)s;
    } else if (gidx == kH * kC + kH) {
        float s = b_cd[0];
        for (int c = 0; c < kC; ++c) s += b_ct[c] * W_cd[c];
        bsc[0] = s;                             // b_sc = b_ct @ W_cd + b_cd
    }
}

// ---------- main: (32768 x 768) @ (768 x 80) bf16 MFMA ----------
// B staged in LDS once per block; 8 waves, each one 16-token full-K tile, no loop
// barriers. A-loads explicitly software-pipelined 2 bodies (128 K-elems) ahead.
__global__ __launch_bounds__(512, 2) void incong_main(
    const float* __restrict__ hs,      // [kTokens][kH] f32
    const bf16*  __restrict__ Wt,      // [>=65][kH] bf16
    const float* __restrict__ bsc_p,
    const float* __restrict__ b_e1,
    const float* __restrict__ W_e2,
    const float* __restrict__ b_e2,
    float* __restrict__ out)           // [3][kTokens]
{
    __shared__ bf16 lds_w[80][kLDW];   // rows 65..79 never written: garbage lands in
                                       // acc[4] cols r16>=1 which the epilogue ignores
    const int tid  = threadIdx.x;
    const int lane = tid & 63;
    const int wv   = tid >> 6;         // 0..7: tile within block
    const int r16  = lane & 15;
    const int kg   = lane >> 4;        // 0..3

    const int tok0 = (blockIdx.x * 8 + wv) * 16;
    const float* ap = hs + (size_t)(tok0 + r16) * kH + kg * 8;

    // ---- issue first two bodies' A-loads BEFORE staging (overlap with B fetch) ----
    float4 a00 = *reinterpret_cast<const float4*>(ap + 0);
    float4 a01 = *reinterpret_cast<const float4*>(ap + 4);
    float4 a10 = *reinterpret_cast<const float4*>(ap + 32);
    float4 a11 = *reinterpret_cast<const float4*>(ap + 36);
    float4 c00 = *reinterpret_cast<const float4*>(ap + 64);
    float4 c01 = *reinterpret_cast<const float4*>(ap + 68);
    float4 c10 = *reinterpret_cast<const float4*>(ap + 96);
    float4 c11 = *reinterpret_cast<const float4*>(ap + 100);

    // ---- stage weight rows 0..64 into LDS (once) ----
    constexpr int kChunks = kNWr * (kH / 8);   // 6240 bf16x8 chunks
    for (int c = tid; c < kChunks; c += 512) {
        int row = c / (kH / 8);
        int col = (c - row * (kH / 8)) * 8;
        *reinterpret_cast<bf16x8*>(&lds_w[row][col]) =
            *reinterpret_cast<const bf16x8*>(&Wt[(size_t)row * kH + col]);
    }
    __syncthreads();

    f32x4 acc[5];
    #pragma unroll
    for (int n = 0; n < 5; ++n) acc[n] = (f32x4){0.f, 0.f, 0.f, 0.f};

    const bf16* lp = &lds_w[r16][kg * 8];

    #pragma unroll
    for (int ks = 0; ks < kH; ks += 64) {      // 12 bodies x 2 MFMA-steps
        float4 n00, n01, n10, n11;
        if (ks < kH - 128) {                   // prefetch 2 bodies ahead
            n00 = *reinterpret_cast<const float4*>(ap + ks + 128);
            n01 = *reinterpret_cast<const float4*>(ap + ks + 132);
            n10 = *reinterpret_cast<const float4*>(ap + ks + 160);
            n11 = *reinterpret_cast<const float4*>(ap + ks + 164);
        }
        bf16x8 af;
        af[0] = (bf16)a00.x; af[1] = (bf16)a00.y; af[2] = (bf16)a00.z; af[3] = (bf16)a00.w;
        af[4] = (bf16)a01.x; af[5] = (bf16)a01.y; af[6] = (bf16)a01.z; af[7] = (bf16)a01.w;
        #pragma unroll
        for (int n = 0; n < 5; ++n) {
            const bf16x8 bfr = *reinterpret_cast<const bf16x8*>(
                lp + (size_t)(n * 16) * kLDW + ks);
            acc[n] = __builtin_amdgcn_mfma_f32_16x16x32_bf16(af, bfr, acc[n], 0, 0, 0);
        }
        bf16x8 ag;
        ag[0] = (bf16)a10.x; ag[1] = (bf16)a10.y; ag[2] = (bf16)a10.z; ag[3] = (bf16)a10.w;
        ag[4] = (bf16)a11.x; ag[5] = (bf16)a11.y; ag[6] = (bf16)a11.z; ag[7] = (bf16)a11.w;
        #pragma unroll
        for (int n = 0; n < 5; ++n) {
            const bf16x8 bfr = *reinterpret_cast<const bf16x8*>(
                lp + (size_t)(n * 16) * kLDW + ks + 32);
            acc[n] = __builtin_amdgcn_mfma_f32_16x16x32_bf16(ag, bfr, acc[n], 0, 0, 0);
        }
        a00 = c00; a01 = c01; a10 = c10; a11 = c11;
        if (ks < kH - 128) { c00 = n00; c01 = n01; c10 = n10; c11 = n11; }
    }

    // ---- epilogue (per wave; D layout: col = lane&15, row = kg*4 + reg) ----
    float part[4] = {0.f, 0.f, 0.f, 0.f};
    #pragma unroll
    for (int n = 0; n < 4; ++n) {
        const int cidx = n * 16 + r16;
        const float be = b_e1[cidx];
        const float we = W_e2[cidx];
        #pragma unroll
        for (int r = 0; r < 4; ++r)
            part[r] += fmaxf(acc[n][r] + be, 0.f) * we;
    }
    #pragma unroll
    for (int m = 1; m < 16; m <<= 1) {
        #pragma unroll
        for (int r = 0; r < 4; ++r) part[r] += __shfl_xor(part[r], m);
    }
    if (r16 == 0) {
        const float bsc = bsc_p[0];
        const float be2 = b_e2[0];
        #pragma unroll
        for (int r = 0; r < 4; ++r) {
            const int tok = tok0 + kg * 4 + r;
            const float sc = acc[4][r] + bsc;          // col 64 = w_sc column
            out[tok]               = 1.f / (1.f + __expf(-sc));
            out[kTokens + tok]     = 1.f / (1.f + __expf(-(part[r] + be2)));
            out[2 * kTokens + tok] = 1.f / 4096.f;     // mean of softmax == 1/S
        }
    }
}

extern "C" void kernel_launch(void* const* d_in, const int* in_sizes, int n_in,
                              void* d_out, int out_size, void* d_ws, size_t ws_size,
                              hipStream_t stream) {
    const float* hs   = (const float*)d_in[0];
    // d_in[1] = attention_mask (all ones, unused by the reference math)
    const float* W_ct = (const float*)d_in[2];
    const float* b_ct = (const float*)d_in[3];
    const float* W_cd = (const float*)d_in[4];
    const float* b_cd = (const float*)d_in[5];
    const float* W_e1 = (const float*)d_in[6];
    const float* b_e1 = (const float*)d_in[7];
    const float* W_e2 = (const float*)d_in[8];
    const float* b_e2 = (const float*)d_in[9];
    // d_in[10..13] = W_q, b_q, W_k, b_k — unused (surprise is exactly 1/S)

    bf16*  Wt  = (bf16*)d_ws;
    float* bsc = (float*)((char*)d_ws + (size_t)80 * kH * sizeof(bf16));

    const int prep_total = kH * kC + kH + 1;    // 49921
    prep_kernel<<<(prep_total + 255) / 256, 256, 0, stream>>>(
        W_ct, b_ct, W_cd, b_cd, W_e1, Wt, bsc);

    incong_main<<<kTokens / (16 * 8), 512, 0, stream>>>(
        hs, Wt, bsc, b_e1, W_e2, b_e2, (float*)d_out);
}